// Round 2
// baseline (102.285 us; speedup 1.0000x reference)
//
#include <hip/hip_runtime.h>
#include <cstdint>
#include <cstddef>

// Problem constants (B=8, H=12, S=1024, D=64)
#define HH 12
#define BH 96          // B*H
#define SS 1024
#define DD 64
#define KT 64          // keys per KV tile
#define NT (SS / KT)   // 16 tiles

typedef __attribute__((ext_vector_type(4))) float f32x4;
typedef __attribute__((ext_vector_type(8))) short bf16x8;

__device__ __forceinline__ unsigned short f2bf(float f) {
    unsigned int x = __builtin_bit_cast(unsigned int, f);
    x += 0x7FFFu + ((x >> 16) & 1u);   // RNE
    return (unsigned short)(x >> 16);
}

// ---------------------------------------------------------------------------
// Flash attention, f32 in / f32 out, bf16 MFMA compute.
// Block = 4 waves; each wave owns 16 q rows (64 q rows / block).
// grid = (S/64, B*H). KV tiles of 64 keys, online softmax in f32.
// LDS layouts (element e of row r stored at [r][e ^ ((r&7)<<3)], 8-granular
// XOR swizzle -> conflict-free ds_read_b128 / ds_write_b128):
//   Klds[key][d]   Vlds[d][key]   Plds[w][q][key]
// ---------------------------------------------------------------------------
__global__ __launch_bounds__(256) void attn_kernel(
        const float* __restrict__ Q,
        const float* __restrict__ Kb,
        const float* __restrict__ Vb,
        const int* __restrict__ mask,
        float* __restrict__ Out) {
    __shared__ unsigned short Klds[KT * DD];     // 8 KB
    __shared__ unsigned short Vlds[DD * KT];     // 8 KB
    __shared__ unsigned short Plds[4][16 * KT];  // 8 KB

    const int tid  = threadIdx.x;
    const int w    = tid >> 6;
    const int lane = tid & 63;
    const int g    = lane >> 4;
    const int l15  = lane & 15;
    const int swq  = (l15 & 7) << 3;

    const int qt = blockIdx.x;
    const int bh = blockIdx.y;
    const int b  = bh / HH;
    const int q0 = qt * 64 + w * 16;

    // ---- Q fragments: f32 load, scale by 1/sqrt(D)=0.125, convert bf16 ----
    bf16x8 qa[2];
    {
        const float* qp = Q + ((size_t)(bh * SS + q0 + l15)) * DD + 8 * g;
#pragma unroll
        for (int c = 0; c < 2; ++c) {
            f32x4 lo = *(const f32x4*)(qp + c * 32);
            f32x4 hi = *(const f32x4*)(qp + c * 32 + 4);
            bf16x8 sq;
#pragma unroll
            for (int j = 0; j < 4; ++j) sq[j]     = (short)f2bf(lo[j] * 0.125f);
#pragma unroll
            for (int j = 0; j < 4; ++j) sq[4 + j] = (short)f2bf(hi[j] * 0.125f);
            qa[c] = sq;
        }
    }

    // ---- staging registers for next KV tile ----
    f32x4 kreg[2][2];      // K: row-major chunks
    float vreg[2][8];      // V: transposed gather (8 k at fixed d)
    auto load_tile_regs = [&](int t) {
#pragma unroll
        for (int i = 0; i < 2; ++i) {
            int c = tid + i * 256;
            {   // K[key=c>>3][d0..d0+7], fully coalesced 32B/lane
                int row = c >> 3, d0 = (c & 7) * 8;
                const float* kp = Kb + ((size_t)(bh * SS + t * KT + row)) * DD + d0;
                kreg[i][0] = *(const f32x4*)kp;
                kreg[i][1] = *(const f32x4*)(kp + 4);
            }
            {   // V[k0+j][d], d = lane index -> coalesced 256B per j-load
                int d = c & 63, k0 = (c >> 6) * 8;
                const float* vp = Vb + ((size_t)(bh * SS + t * KT + k0)) * DD + d;
#pragma unroll
                for (int j = 0; j < 8; ++j) vreg[i][j] = vp[(size_t)j * DD];
            }
        }
    };
    auto write_tile_lds = [&]() {
#pragma unroll
        for (int i = 0; i < 2; ++i) {
            int c = tid + i * 256;
            {
                int row = c >> 3, d0 = (c & 7) * 8;
                bf16x8 kv;
#pragma unroll
                for (int j = 0; j < 4; ++j) kv[j]     = (short)f2bf(kreg[i][0][j]);
#pragma unroll
                for (int j = 0; j < 4; ++j) kv[4 + j] = (short)f2bf(kreg[i][1][j]);
                *(bf16x8*)&Klds[row * DD + (d0 ^ ((row & 7) << 3))] = kv;
            }
            {
                int d = c & 63, k0 = (c >> 6) * 8;
                bf16x8 vv;
#pragma unroll
                for (int j = 0; j < 8; ++j) vv[j] = (short)f2bf(vreg[i][j]);
                *(bf16x8*)&Vlds[d * KT + (k0 ^ ((d & 7) << 3))] = vv;
            }
        }
    };

    f32x4 Oacc[4];
#pragma unroll
    for (int dt = 0; dt < 4; ++dt) Oacc[dt] = (f32x4){0.f, 0.f, 0.f, 0.f};
    float mrow[4], lrow[4];
#pragma unroll
    for (int r = 0; r < 4; ++r) { mrow[r] = -3.0e38f; lrow[r] = 0.f; }

    load_tile_regs(0);

    for (int t = 0; t < NT; ++t) {
        __syncthreads();          // all waves done reading previous tile
        write_tile_lds();
        __syncthreads();          // tile t visible
        if (t + 1 < NT) load_tile_regs(t + 1);   // overlap next loads

        // per-key mask add: key = t*64 + 16n + l15
        float madd[4];
#pragma unroll
        for (int n = 0; n < 4; ++n) {
            int mk = mask[b * SS + t * KT + 16 * n + l15];
            madd[n] = mk ? 0.0f : -1.0e6f;
        }

        // ---- QK^T: D[q=4g+r][key=16n+l15] ----
        f32x4 s4[4];
#pragma unroll
        for (int n = 0; n < 4; ++n) {
            f32x4 acc = (f32x4){0.f, 0.f, 0.f, 0.f};
#pragma unroll
            for (int c = 0; c < 2; ++c) {
                bf16x8 kb = *(const bf16x8*)
                    &Klds[(16 * n + l15) * DD + ((c * 32 + 8 * g) ^ swq)];
                acc = __builtin_amdgcn_mfma_f32_16x16x32_bf16(qa[c], kb, acc, 0, 0, 0);
            }
#pragma unroll
            for (int r = 0; r < 4; ++r) s4[n][r] = acc[r] + madd[n];
        }

        // ---- online softmax (row q=4g+r lives on the 16 lanes of group g) ----
        float tmax[4];
#pragma unroll
        for (int r = 0; r < 4; ++r)
            tmax[r] = fmaxf(fmaxf(s4[0][r], s4[1][r]), fmaxf(s4[2][r], s4[3][r]));
#pragma unroll
        for (int r = 0; r < 4; ++r)
#pragma unroll
            for (int msk = 1; msk < 16; msk <<= 1)
                tmax[r] = fmaxf(tmax[r], __shfl_xor(tmax[r], msk));

        float corr[4], tsum[4], p[4][4];
#pragma unroll
        for (int r = 0; r < 4; ++r) {
            float mnew = fmaxf(mrow[r], tmax[r]);
            corr[r] = __expf(mrow[r] - mnew);
            mrow[r] = mnew;
            tsum[r] = 0.f;
        }
#pragma unroll
        for (int n = 0; n < 4; ++n)
#pragma unroll
            for (int r = 0; r < 4; ++r) {
                float pv = __expf(s4[n][r] - mrow[r]);
                p[n][r] = pv;
                tsum[r] += pv;
            }
#pragma unroll
        for (int r = 0; r < 4; ++r) {
#pragma unroll
            for (int msk = 1; msk < 16; msk <<= 1)
                tsum[r] += __shfl_xor(tsum[r], msk);
            lrow[r] = lrow[r] * corr[r] + tsum[r];
        }
#pragma unroll
        for (int dt = 0; dt < 4; ++dt)
#pragma unroll
            for (int r = 0; r < 4; ++r) Oacc[dt][r] *= corr[r];

        // ---- P -> LDS (bf16, swizzled), then PV ----
#pragma unroll
        for (int n = 0; n < 4; ++n) {
            int key = 16 * n + l15;
#pragma unroll
            for (int r = 0; r < 4; ++r) {
                int q = 4 * g + r;
                Plds[w][q * KT + (key ^ ((q & 7) << 3))] = f2bf(p[n][r]);
            }
        }
#pragma unroll
        for (int ks = 0; ks < 2; ++ks) {
            bf16x8 pa = *(const bf16x8*)&Plds[w][l15 * KT + ((ks * 32 + 8 * g) ^ swq)];
#pragma unroll
            for (int dt = 0; dt < 4; ++dt) {
                bf16x8 vb = *(const bf16x8*)
                    &Vlds[(dt * 16 + l15) * KT + ((ks * 32 + 8 * g) ^ swq)];
                Oacc[dt] = __builtin_amdgcn_mfma_f32_16x16x32_bf16(pa, vb, Oacc[dt], 0, 0, 0);
            }
        }
    }

    // ---- epilogue: divide by l, store f32 ----
    float inv[4];
#pragma unroll
    for (int r = 0; r < 4; ++r) inv[r] = 1.0f / lrow[r];
#pragma unroll
    for (int dt = 0; dt < 4; ++dt)
#pragma unroll
        for (int r = 0; r < 4; ++r) {
            size_t o = ((size_t)(bh * SS + q0 + 4 * g + r)) * DD + dt * 16 + l15;
            Out[o] = Oacc[dt][r] * inv[r];
        }
}

extern "C" void kernel_launch(void* const* d_in, const int* in_sizes, int n_in,
                              void* d_out, int out_size, void* d_ws, size_t ws_size,
                              hipStream_t stream) {
    const float* Q   = (const float*)d_in[0];
    const float* K   = (const float*)d_in[1];
    const float* V   = (const float*)d_in[2];
    const int* mask  = (const int*)d_in[5];
    float* out       = (float*)d_out;

    attn_kernel<<<dim3(SS / 64, BH), 256, 0, stream>>>(Q, K, V, mask, out);
}

// Round 4
// 92.450 us; speedup vs baseline: 1.1064x; 1.1064x over previous
//
#include <hip/hip_runtime.h>
#include <hip/hip_bf16.h>
#include <cstdint>
#include <cstddef>

// Problem constants (B=8, H=12, S=1024, D=64)
#define HH 12
#define BH 96          // B*H
#define SS 1024
#define DD 64
#define KT 64          // keys per KV tile
#define NT (SS / KT)   // 16 tiles
#define QB 128         // q rows per block (2 q-tiles)
#define NQT (SS / QB)  // 8

typedef __attribute__((ext_vector_type(4))) float f32x4;
typedef __attribute__((ext_vector_type(8))) short bf16x8;
typedef __attribute__((ext_vector_type(4))) int   i32x4;

#define SCL  0.1803368801111204f   // 0.125 * log2(e)  -> exp2 domain
#define NEGL 1442695.0f            // 1e6  * log2(e)

__device__ __forceinline__ unsigned int pk2(float lo, float hi) {
    __hip_bfloat162 h = __float22bfloat162_rn(float2{lo, hi});
    unsigned int u;
    __builtin_memcpy(&u, &h, sizeof(u));   // v_cvt_pk_bf16_f32 + reg move
    return u;
}

// ---------------------------------------------------------------------------
// Flash attention, f32 in/out, bf16 MFMA. Block = 4 waves, 128 q rows
// (each wave: two 16-row fragments). grid = (bh, qt) so same-bh blocks share
// an XCD's L2 (96 % 8 == 0). KV tiles of 64 keys, online softmax in exp2
// domain. XOR-swizzled LDS (elem e of row r at [r][e ^ ((r&7)<<3)]).
// ---------------------------------------------------------------------------
__global__ __launch_bounds__(256, 3) void attn_kernel(
        const float* __restrict__ Q,
        const float* __restrict__ Kb,
        const float* __restrict__ Vb,
        const int* __restrict__ mask,
        float* __restrict__ Out) {
    __shared__ unsigned short Klds[KT * DD];     // 8 KB
    __shared__ unsigned short Vlds[DD * KT];     // 8 KB
    __shared__ unsigned short Plds[4][16 * KT];  // 8 KB
    __shared__ float Madd[SS];                   // 4 KB  (log2-domain mask add)

    const int tid  = threadIdx.x;
    const int w    = tid >> 6;
    const int lane = tid & 63;
    const int g    = lane >> 4;
    const int l15  = lane & 15;
    const int swq  = (l15 & 7) << 3;

    const int bh = blockIdx.x;
    const int qt = blockIdx.y;
    const int b  = bh / HH;

    // ---- mask table (once per block) ----
    {
        i32x4 m4 = *(const i32x4*)(mask + b * SS + tid * 4);
        f32x4 a;
#pragma unroll
        for (int j = 0; j < 4; ++j) a[j] = m4[j] ? 0.0f : -NEGL;
        *(f32x4*)&Madd[tid * 4] = a;
    }

    // ---- Q fragments (both halves), scaled into exp2 domain ----
    bf16x8 qa[2][2];
#pragma unroll
    for (int h = 0; h < 2; ++h) {
        const float* qp = Q + ((size_t)(bh * SS + qt * QB + h * 64 + w * 16 + l15)) * DD + 8 * g;
#pragma unroll
        for (int c = 0; c < 2; ++c) {
            f32x4 lo = *(const f32x4*)(qp + c * 32);
            f32x4 hi = *(const f32x4*)(qp + c * 32 + 4);
            union { bf16x8 v; unsigned int u[4]; } o;
            o.u[0] = pk2(lo[0] * SCL, lo[1] * SCL);
            o.u[1] = pk2(lo[2] * SCL, lo[3] * SCL);
            o.u[2] = pk2(hi[0] * SCL, hi[1] * SCL);
            o.u[3] = pk2(hi[2] * SCL, hi[3] * SCL);
            qa[h][c] = o.v;
        }
    }

    // ---- staging registers for next KV tile ----
    f32x4 kreg[2][2];
    float vreg[2][8];
    auto load_tile_regs = [&](int t) {
#pragma unroll
        for (int i = 0; i < 2; ++i) {
            int c = tid + i * 256;
            {   // K[key][d0..d0+7], coalesced 32B/lane
                int row = c >> 3, d0 = (c & 7) * 8;
                const float* kp = Kb + ((size_t)(bh * SS + t * KT + row)) * DD + d0;
                kreg[i][0] = *(const f32x4*)kp;
                kreg[i][1] = *(const f32x4*)(kp + 4);
            }
            {   // V^T gather: 8 keys at fixed d (d = lane -> 256B coalesced per j)
                int d = c & 63, k0 = (c >> 6) * 8;
                const float* vp = Vb + ((size_t)(bh * SS + t * KT + k0)) * DD + d;
#pragma unroll
                for (int j = 0; j < 8; ++j) vreg[i][j] = vp[(size_t)j * DD];
            }
        }
    };
    auto write_tile_lds = [&]() {
#pragma unroll
        for (int i = 0; i < 2; ++i) {
            int c = tid + i * 256;
            {
                int row = c >> 3, d0 = (c & 7) * 8;
                union { bf16x8 v; unsigned int u[4]; } kv;
                kv.u[0] = pk2(kreg[i][0][0], kreg[i][0][1]);
                kv.u[1] = pk2(kreg[i][0][2], kreg[i][0][3]);
                kv.u[2] = pk2(kreg[i][1][0], kreg[i][1][1]);
                kv.u[3] = pk2(kreg[i][1][2], kreg[i][1][3]);
                *(bf16x8*)&Klds[row * DD + (d0 ^ ((row & 7) << 3))] = kv.v;
            }
            {
                int d = c & 63, k0 = (c >> 6) * 8;
                union { bf16x8 v; unsigned int u[4]; } vv;
                vv.u[0] = pk2(vreg[i][0], vreg[i][1]);
                vv.u[1] = pk2(vreg[i][2], vreg[i][3]);
                vv.u[2] = pk2(vreg[i][4], vreg[i][5]);
                vv.u[3] = pk2(vreg[i][6], vreg[i][7]);
                *(bf16x8*)&Vlds[d * KT + (k0 ^ ((d & 7) << 3))] = vv.v;
            }
        }
    };

    f32x4 Oacc[2][4];
    float mrow[2][4], lrow[2][4];
#pragma unroll
    for (int h = 0; h < 2; ++h) {
#pragma unroll
        for (int dt = 0; dt < 4; ++dt) Oacc[h][dt] = (f32x4){0.f, 0.f, 0.f, 0.f};
#pragma unroll
        for (int r = 0; r < 4; ++r) { mrow[h][r] = -3.0e38f; lrow[h][r] = 0.f; }
    }

    load_tile_regs(0);

    for (int t = 0; t < NT; ++t) {
        __syncthreads();                 // readers of tile t-1 done; Madd visible at t=0
        write_tile_lds();
        __syncthreads();                 // tile t visible
        if (t + 1 < NT) load_tile_regs(t + 1);

        float madd[4];
#pragma unroll
        for (int n = 0; n < 4; ++n) madd[n] = Madd[t * KT + 16 * n + l15];

#pragma unroll
        for (int h = 0; h < 2; ++h) {
            // ---- QK^T: s4[n][r] = score[q=4g+r][key=16n+l15] (log2 domain) ----
            f32x4 s4[4];
            __builtin_amdgcn_s_setprio(1);
#pragma unroll
            for (int n = 0; n < 4; ++n) {
                f32x4 acc = (f32x4){0.f, 0.f, 0.f, 0.f};
#pragma unroll
                for (int c = 0; c < 2; ++c) {
                    bf16x8 kb = *(const bf16x8*)
                        &Klds[(16 * n + l15) * DD + ((c * 32 + 8 * g) ^ swq)];
                    acc = __builtin_amdgcn_mfma_f32_16x16x32_bf16(qa[h][c], kb, acc, 0, 0, 0);
                }
#pragma unroll
                for (int r = 0; r < 4; ++r) s4[n][r] = acc[r] + madd[n];
            }
            __builtin_amdgcn_s_setprio(0);

            // ---- online softmax (row q=4g+r on the 16 lanes of group g) ----
            float tmax[4];
#pragma unroll
            for (int r = 0; r < 4; ++r)
                tmax[r] = fmaxf(fmaxf(s4[0][r], s4[1][r]), fmaxf(s4[2][r], s4[3][r]));
#pragma unroll
            for (int r = 0; r < 4; ++r)
#pragma unroll
                for (int msk = 1; msk < 16; msk <<= 1)
                    tmax[r] = fmaxf(tmax[r], __shfl_xor(tmax[r], msk));

            float corr[4], tsum[4];
#pragma unroll
            for (int r = 0; r < 4; ++r) {
                float mnew = fmaxf(mrow[h][r], tmax[r]);
                corr[r] = exp2f(mrow[h][r] - mnew);
                mrow[h][r] = mnew;
                tsum[r] = 0.f;
            }
            // p = exp2(s - m), accumulate sum, write bf16 P to LDS (swizzled)
#pragma unroll
            for (int n = 0; n < 4; ++n) {
                int key = 16 * n + l15;
                float pv[4];
#pragma unroll
                for (int r = 0; r < 4; ++r) {
                    pv[r] = exp2f(s4[n][r] - mrow[h][r]);
                    tsum[r] += pv[r];
                }
                unsigned int w01 = pk2(pv[0], pv[1]);
                unsigned int w23 = pk2(pv[2], pv[3]);
                Plds[w][(4 * g + 0) * KT + (key ^ (((4 * g + 0) & 7) << 3))] = (unsigned short)(w01 & 0xffff);
                Plds[w][(4 * g + 1) * KT + (key ^ (((4 * g + 1) & 7) << 3))] = (unsigned short)(w01 >> 16);
                Plds[w][(4 * g + 2) * KT + (key ^ (((4 * g + 2) & 7) << 3))] = (unsigned short)(w23 & 0xffff);
                Plds[w][(4 * g + 3) * KT + (key ^ (((4 * g + 3) & 7) << 3))] = (unsigned short)(w23 >> 16);
            }
#pragma unroll
            for (int r = 0; r < 4; ++r) {
#pragma unroll
                for (int msk = 1; msk < 16; msk <<= 1)
                    tsum[r] += __shfl_xor(tsum[r], msk);
                lrow[h][r] = lrow[h][r] * corr[r] + tsum[r];
            }
#pragma unroll
            for (int dt = 0; dt < 4; ++dt)
#pragma unroll
                for (int r = 0; r < 4; ++r) Oacc[h][dt][r] *= corr[r];

            // ---- PV ----
            __builtin_amdgcn_s_setprio(1);
#pragma unroll
            for (int ks = 0; ks < 2; ++ks) {
                bf16x8 pa = *(const bf16x8*)&Plds[w][l15 * KT + ((ks * 32 + 8 * g) ^ swq)];
#pragma unroll
                for (int dt = 0; dt < 4; ++dt) {
                    bf16x8 vb = *(const bf16x8*)
                        &Vlds[(dt * 16 + l15) * KT + ((ks * 32 + 8 * g) ^ swq)];
                    Oacc[h][dt] = __builtin_amdgcn_mfma_f32_16x16x32_bf16(pa, vb, Oacc[h][dt], 0, 0, 0);
                }
            }
            __builtin_amdgcn_s_setprio(0);
        }
    }

    // ---- epilogue ----
#pragma unroll
    for (int h = 0; h < 2; ++h) {
        float inv[4];
#pragma unroll
        for (int r = 0; r < 4; ++r) inv[r] = 1.0f / lrow[h][r];
        const size_t rowbase = (size_t)(bh * SS + qt * QB + h * 64 + w * 16);
#pragma unroll
        for (int dt = 0; dt < 4; ++dt)
#pragma unroll
            for (int r = 0; r < 4; ++r)
                Out[(rowbase + 4 * g + r) * DD + dt * 16 + l15] = Oacc[h][dt][r] * inv[r];
    }
}

extern "C" void kernel_launch(void* const* d_in, const int* in_sizes, int n_in,
                              void* d_out, int out_size, void* d_ws, size_t ws_size,
                              hipStream_t stream) {
    const float* Q   = (const float*)d_in[0];
    const float* K   = (const float*)d_in[1];
    const float* V   = (const float*)d_in[2];
    const int* mask  = (const int*)d_in[5];
    float* out       = (float*)d_out;

    // grid.x = bh so the 8 q-tile blocks of one (b,h) share an XCD (96 % 8 == 0)
    attn_kernel<<<dim3(BH, NQT), 256, 0, stream>>>(Q, K, V, mask, out);
}